// Round 2
// baseline (282.939 us; speedup 1.0000x reference)
//
#include <hip/hip_runtime.h>

// Problem: B=64, T=512, H=768, C=21
// inputs: hidden(64*512*768 f32), W(768*21 f32), b(21), start(21), end(21),
//         trans(21*21 f32), labels(64*512 int32, -100 = masked, prefix-valid)
// output: scalar f32 loss = mean_b(logZ_b - num_b)

#define T_LEN 512
#define C_NUM 21
#define H_DIM 768
#define B_NUM 64
#define WT_LD 772  // padded leading dim for transposed W in LDS (mult of 4 for b128 alignment)

__device__ __forceinline__ float lane_bcast(float v, int l) {
    return __int_as_float(__builtin_amdgcn_readlane(__float_as_int(v), l));
}

// ---------------- Kernel 1: emissions = hidden @ W + b (valid rows only) ----------------
// grid: 1024 blocks x 256 threads; each block: 32 rows (2 iters x 4 waves x 4 rows)
__global__ __launch_bounds__(256) void emis_kernel(
    const float* __restrict__ hidden, const float* __restrict__ W,
    const float* __restrict__ bvec, const int* __restrict__ labels,
    float* __restrict__ ems)
{
    __shared__ __align__(16) float Wt[C_NUM * WT_LD]; // 21*772*4 = 64848 B
    __shared__ float blds[C_NUM];

    const int tid = threadIdx.x;
    // Stage W transposed, coalesced global reads: lin -> (k = lin/21, c = lin%21)
    for (int lin = tid; lin < H_DIM * C_NUM; lin += 256) {
        const int k = lin / C_NUM;           // magic-mul, no HW divide
        const int c = lin - k * C_NUM;
        Wt[c * WT_LD + k] = W[lin];
    }
    if (tid < C_NUM) blds[tid] = bvec[tid];
    __syncthreads();

    const int wid  = tid >> 6;       // wave 0..3
    const int lane = tid & 63;
    const int rl   = lane >> 4;      // row within wave 0..3
    const int q    = lane & 15;      // 16 lanes per row

    #pragma unroll
    for (int iter = 0; iter < 2; ++iter) {
        const int row = blockIdx.x * 32 + iter * 16 + wid * 4 + rl;
        const int lab = labels[row];
        const bool valid = (lab != -100);

        float acc[C_NUM];
        #pragma unroll
        for (int c = 0; c < C_NUM; ++c) acc[c] = 0.f;

        if (valid) {
            const float4* hp = (const float4*)(hidden + (size_t)row * H_DIM);
            #pragma unroll
            for (int m = 0; m < 12; ++m) {
                const float4 h = hp[m * 16 + q];   // coalesced: 16 lanes cover 256B of row
                #pragma unroll
                for (int c = 0; c < C_NUM; ++c) {
                    // 16 lanes read 64 consecutive dwords of row c: 2-way bank alias = free;
                    // 4 row-groups read same addr = broadcast.
                    const float4 w = *(const float4*)&Wt[c * WT_LD + m * 64 + q * 4];
                    acc[c] = fmaf(h.w, w.w, fmaf(h.z, w.z, fmaf(h.y, w.y, fmaf(h.x, w.x, acc[c]))));
                }
            }
        }

        // reduce over the 16 lanes of each row group; lane q==0 stores
        #pragma unroll
        for (int c = 0; c < C_NUM; ++c) {
            float v = acc[c];
            v += __shfl_xor(v, 1);
            v += __shfl_xor(v, 2);
            v += __shfl_xor(v, 4);
            v += __shfl_xor(v, 8);
            if (q == 0 && valid) ems[(size_t)row * C_NUM + c] = v + blds[c];
        }
    }
}

// ---------------- Kernel 2: per-batch CRF forward scan + numerator ----------------
// grid: 64 blocks x 64 threads (one wave per batch; latency-bound serial scan)
__global__ __launch_bounds__(64) void crf_kernel(
    const float* __restrict__ ems, const int* __restrict__ labels,
    const float* __restrict__ start, const float* __restrict__ endv,
    const float* __restrict__ trans, float* __restrict__ out)
{
    const int b    = blockIdx.x;
    const int lane = threadIdx.x;
    const int*   lab = labels + b * T_LEN;
    const float* em  = ems + (size_t)b * T_LEN * C_NUM;

    // ---- numerator + length (all 64 lanes, strided over t; mask is a prefix) ----
    int   cnt = 0;
    float s   = 0.f;
    for (int t = lane; t < T_LEN; t += 64) {
        const int lt = lab[t];
        if (lt != -100) {
            cnt++;
            s += em[t * C_NUM + lt];
            if (t == 0) s += start[lt];
            else        s += trans[lab[t - 1] * C_NUM + lt];
        }
    }
    #pragma unroll
    for (int o = 32; o; o >>= 1) {
        s   += __shfl_xor(s, o);
        cnt += __shfl_xor(cnt, o);
    }
    const int len = cnt;                       // prefix mask: len = #valid, >= T/2
    const float num = s + endv[lab[len - 1]];

    // ---- forward scan: lane j owns alpha_j (shifted); E columns in registers ----
    const int j = lane;
    float Ecol[C_NUM];
    float alpha;
    if (j < C_NUM) {
        #pragma unroll
        for (int i = 0; i < C_NUM; ++i) Ecol[i] = __expf(trans[i * C_NUM + j]);
        alpha = start[j] + em[j];
    } else {
        #pragma unroll
        for (int i = 0; i < C_NUM; ++i) Ecol[i] = 0.f;
        alpha = -1e30f;
    }

    float Sacc = 0.f;
    // 2-deep emission prefetch (ems is cross-XCD L2-miss: ~300-400 cy)
    float em_n1 = (j < C_NUM && len > 1) ? em[1 * C_NUM + j] : 0.f;
    float em_n2 = (j < C_NUM && len > 2) ? em[2 * C_NUM + j] : 0.f;

    for (int t = 1; t < len; ++t) {
        const float em_cur = em_n1;
        em_n1 = em_n2;
        if (t + 2 < len && j < C_NUM) em_n2 = em[(t + 2) * C_NUM + j];

        // shift by first lane's alpha (state spread bounded ~±3 → exp safe)
        const float M = __int_as_float(__builtin_amdgcn_readfirstlane(__float_as_int(alpha)));
        const float v = __expf(alpha - M);

        float y0 = 0.f, y1 = 0.f, y2 = 0.f, y3 = 0.f;
        #pragma unroll
        for (int i = 0; i < C_NUM; i += 4) {
            y0 = fmaf(lane_bcast(v, i), Ecol[i], y0);
            if (i + 1 < C_NUM) y1 = fmaf(lane_bcast(v, i + 1), Ecol[i + 1], y1);
            if (i + 2 < C_NUM) y2 = fmaf(lane_bcast(v, i + 2), Ecol[i + 2], y2);
            if (i + 3 < C_NUM) y3 = fmaf(lane_bcast(v, i + 3), Ecol[i + 3], y3);
        }
        alpha = __logf((y0 + y1) + (y2 + y3)) + em_cur;
        Sacc += M;
    }

    // ---- logZ = Sacc + logsumexp_j(alpha_j + end_j) ----
    float x = (j < C_NUM) ? (alpha + endv[j]) : -1e30f;
    float xm = x;
    #pragma unroll
    for (int o = 32; o; o >>= 1) xm = fmaxf(xm, __shfl_xor(xm, o));
    float e = __expf(x - xm);
    #pragma unroll
    for (int o = 32; o; o >>= 1) e += __shfl_xor(e, o);

    if (lane == 0) {
        const float logZ = Sacc + xm + __logf(e);
        atomicAdd(out, (logZ - num) * (1.0f / (float)B_NUM));
    }
}

// ---------------- host launch ----------------
extern "C" void kernel_launch(void* const* d_in, const int* in_sizes, int n_in,
                              void* d_out, int out_size, void* d_ws, size_t ws_size,
                              hipStream_t stream) {
    const float* hidden = (const float*)d_in[0];
    const float* W      = (const float*)d_in[1];
    const float* bvec   = (const float*)d_in[2];
    const float* start  = (const float*)d_in[3];
    const float* endv   = (const float*)d_in[4];
    const float* trans  = (const float*)d_in[5];
    const int*   labels = (const int*)d_in[6];

    float* ems  = (float*)d_ws;              // 64*512*21 f32 = 2.75 MB
    float* outp = (float*)d_out;

    hipMemsetAsync(outp, 0, sizeof(float), stream);

    emis_kernel<<<dim3((B_NUM * T_LEN) / 32), dim3(256), 0, stream>>>(
        hidden, W, bvec, labels, ems);

    crf_kernel<<<dim3(B_NUM), dim3(64), 0, stream>>>(
        ems, labels, start, endv, trans, outp);
}

// Round 5
// 242.557 us; speedup vs baseline: 1.1665x; 1.1665x over previous
//
#include <hip/hip_runtime.h>

// Problem: B=64, T=512, H=768, C=21
// inputs: hidden(64*512*768 f32), W(768*21 f32), b(21), start(21), end(21),
//         trans(21*21 f32), labels(64*512 int32, -100 = masked, prefix-valid)
// output: scalar f32 loss = mean_b(logZ_b - num_b)

#define T_LEN 512
#define C_NUM 21
#define H_DIM 768
#define B_NUM 64
#define WT_LD 772  // padded leading dim for transposed W in LDS

__device__ __forceinline__ float bcastf(float v, int l) {
    return __int_as_float(__builtin_amdgcn_readlane(__float_as_int(v), l));
}
__device__ __forceinline__ float firstf(float v) {
    return __int_as_float(__builtin_amdgcn_readfirstlane(__float_as_int(v)));
}

// ---------------- Kernel 1: emissions = hidden @ W + b ----------------
// grid: 512 blocks x 256 threads; block: 64 rows. Wave: 16 rows.
// Row-group rl (lane>>4): 4 rows register-blocked per lane; q = lane&15 is k-slice.
// Each W ds_read_b128 is reused by 4 row FMAs (and broadcast across 4 groups).
__global__ __launch_bounds__(256) void emis_kernel(
    const float* __restrict__ hidden, const float* __restrict__ W,
    const float* __restrict__ bvec, const int* __restrict__ labels,
    float* __restrict__ ems, float* __restrict__ out)
{
    __shared__ __align__(16) float Wt[C_NUM * WT_LD]; // 64848 B
    __shared__ float blds[C_NUM];

    const int tid = threadIdx.x;
    if (blockIdx.x == 0 && tid == 0) out[0] = 0.f;  // init for crf atomics (stream-ordered)

    // Stage W transposed; coalesced global reads, scattered LDS writes (one-time)
    for (int lin = tid; lin < H_DIM * C_NUM; lin += 256) {
        const int k = lin / C_NUM;            // magic-mul
        const int c = lin - k * C_NUM;
        Wt[c * WT_LD + k] = W[lin];
    }
    if (tid < C_NUM) blds[tid] = bvec[tid];
    __syncthreads();

    const int wid  = tid >> 6;
    const int lane = tid & 63;
    const int rl   = lane >> 4;
    const int q    = lane & 15;
    const int r0   = blockIdx.x * 64 + wid * 16 + rl * 4;  // 4 rows per lane

    bool v[4];
    bool anyv = false;
    #pragma unroll
    for (int rr = 0; rr < 4; ++rr) {
        v[rr] = (labels[r0 + rr] != -100);
        anyv = anyv || v[rr];
    }

    float acc[4][C_NUM];
    #pragma unroll
    for (int rr = 0; rr < 4; ++rr)
        #pragma unroll
        for (int c = 0; c < C_NUM; ++c) acc[rr][c] = 0.f;

    if (anyv) {
        #pragma unroll 2
        for (int m = 0; m < 12; ++m) {
            float4 h[4];
            #pragma unroll
            for (int rr = 0; rr < 4; ++rr)
                h[rr] = *(const float4*)&hidden[(size_t)(r0 + rr) * H_DIM + m * 64 + q * 4];
            #pragma unroll
            for (int c = 0; c < C_NUM; ++c) {
                const float4 w = *(const float4*)&Wt[c * WT_LD + m * 64 + q * 4];
                #pragma unroll
                for (int rr = 0; rr < 4; ++rr) {
                    acc[rr][c] = fmaf(h[rr].w, w.w, fmaf(h[rr].z, w.z,
                                 fmaf(h[rr].y, w.y, fmaf(h[rr].x, w.x, acc[rr][c]))));
                }
            }
        }
    }

    // reduce over the 16 k-slice lanes of each row group
    #pragma unroll
    for (int rr = 0; rr < 4; ++rr) {
        #pragma unroll
        for (int c = 0; c < C_NUM; ++c) {
            float s = acc[rr][c];
            s += __shfl_xor(s, 1);
            s += __shfl_xor(s, 2);
            s += __shfl_xor(s, 4);
            s += __shfl_xor(s, 8);
            acc[rr][c] = s;
        }
    }
    if (q == 0) {
        #pragma unroll
        for (int rr = 0; rr < 4; ++rr) {
            if (v[rr]) {
                float* er = ems + (size_t)(r0 + rr) * C_NUM;
                #pragma unroll
                for (int c = 0; c < C_NUM; ++c) er[c] = acc[rr][c] + blds[c];
            }
        }
    }
}

// ---------------- Kernel 2: CRF forward scan (linear space) + numerator ----------------
// grid: 64 blocks x 64 threads. Lane j owns state j. Scan runs in LINEAR space:
// a_j <- (sum_i a_i * E_ij) * exp(em_t_j); exp(em) is precomputed 2 steps ahead
// (off the serial chain); power-of-2 rescale every 8 steps (exact, lane-0 exponent).
// Removes both transcendentals (exp+log) from the loop-carried critical path.
__global__ __launch_bounds__(64) void crf_kernel(
    const float* __restrict__ ems, const int* __restrict__ labels,
    const float* __restrict__ start, const float* __restrict__ endv,
    const float* __restrict__ trans, float* __restrict__ out)
{
    const int b    = blockIdx.x;
    const int lane = threadIdx.x;
    const int*   lab = labels + b * T_LEN;
    const float* em  = ems + (size_t)b * T_LEN * C_NUM;

    // ---- numerator + length (mask is a prefix; len >= T/2) ----
    int   cnt = 0;
    float s   = 0.f;
    for (int t = lane; t < T_LEN; t += 64) {
        const int lt = lab[t];
        if (lt != -100) {
            cnt++;
            s += em[t * C_NUM + lt];
            if (t == 0) s += start[lt];
            else        s += trans[lab[t - 1] * C_NUM + lt];
        }
    }
    #pragma unroll
    for (int o = 32; o; o >>= 1) {
        s   += __shfl_xor(s, o);
        cnt += __shfl_xor(cnt, o);
    }
    const int len = cnt;
    const float num = s + endv[lab[len - 1]];

    // ---- linear-space forward scan ----
    const int j = lane;
    float Ecol[C_NUM];
    float al0 = -1e30f;
    if (j < C_NUM) {
        #pragma unroll
        for (int i = 0; i < C_NUM; ++i) Ecol[i] = __expf(trans[i * C_NUM + j]);
        al0 = start[j] + em[j];
    } else {
        #pragma unroll
        for (int i = 0; i < C_NUM; ++i) Ecol[i] = 0.f;
    }
    const float M0 = firstf(al0);
    float a = __expf(al0 - M0);          // lanes >= 21: exp(-huge) = 0
    double Sacc = (double)M0;

    // emission prefetch pipeline (2 deep); lanes >= 21 read a safe dummy column
    const float* ep = em + ((j < C_NUM) ? j : 0);
    float raw2 = ep[1 * C_NUM];          // em for t=1 (len >= 256 guaranteed)
    float eem1 = __expf(raw2);           // exp(em[1])
    raw2 = ep[2 * C_NUM];                // em for t=2

    #pragma unroll 2
    for (int t = 1; t < len; ++t) {
        const int idx = (t + 2 < len) ? (t + 2) : (len - 1);
        const float rawn = ep[idx * C_NUM];   // load for t+2 (always safe address)
        const float eem_cur = eem1;           // exp(em[t])
        eem1 = __expf(raw2);                  // exp(em[t+1]) — off critical path
        raw2 = rawn;

        // 8 independent FMA chains (depth <= 3) + 3-level add tree:
        // shortest provable dep path for the 21-term matvec.
        float y0 = 0.f, y1 = 0.f, y2 = 0.f, y3 = 0.f;
        float y4 = 0.f, y5 = 0.f, y6 = 0.f, y7 = 0.f;
        #pragma unroll
        for (int i = 0; i < 16; i += 8) {
            y0 = fmaf(bcastf(a, i + 0), Ecol[i + 0], y0);
            y1 = fmaf(bcastf(a, i + 1), Ecol[i + 1], y1);
            y2 = fmaf(bcastf(a, i + 2), Ecol[i + 2], y2);
            y3 = fmaf(bcastf(a, i + 3), Ecol[i + 3], y3);
            y4 = fmaf(bcastf(a, i + 4), Ecol[i + 4], y4);
            y5 = fmaf(bcastf(a, i + 5), Ecol[i + 5], y5);
            y6 = fmaf(bcastf(a, i + 6), Ecol[i + 6], y6);
            y7 = fmaf(bcastf(a, i + 7), Ecol[i + 7], y7);
        }
        y0 = fmaf(bcastf(a, 16), Ecol[16], y0);
        y1 = fmaf(bcastf(a, 17), Ecol[17], y1);
        y2 = fmaf(bcastf(a, 18), Ecol[18], y2);
        y3 = fmaf(bcastf(a, 19), Ecol[19], y3);
        y4 = fmaf(bcastf(a, 20), Ecol[20], y4);
        a = (((y0 + y1) + (y2 + y3)) + ((y4 + y5) + (y6 + y7))) * eem_cur;

        if ((t & 7) == 7) {                   // exact power-of-2 rescale
            const float m = firstf(a);
            const int ebits = (__float_as_int(m) >> 23) & 0xff;
            a *= __int_as_float((254 - ebits) << 23);       // a *= 2^(127-ebits)
            Sacc += (double)(ebits - 127) * 0.6931471805599453;
        }
    }

    // ---- logZ = Sacc + log(sum_j a_j * exp(end_j)) ----
    float x = 0.f;
    if (j < C_NUM) x = a * __expf(endv[j]);
    float e = x;
    #pragma unroll
    for (int o = 32; o; o >>= 1) e += __shfl_xor(e, o);

    if (lane == 0) {
        const float logZ = (float)(Sacc + (double)__logf(e));
        atomicAdd(out, (logZ - num) * (1.0f / (float)B_NUM));
    }
}

// ---------------- host launch ----------------
extern "C" void kernel_launch(void* const* d_in, const int* in_sizes, int n_in,
                              void* d_out, int out_size, void* d_ws, size_t ws_size,
                              hipStream_t stream) {
    const float* hidden = (const float*)d_in[0];
    const float* W      = (const float*)d_in[1];
    const float* bvec   = (const float*)d_in[2];
    const float* start  = (const float*)d_in[3];
    const float* endv   = (const float*)d_in[4];
    const float* trans  = (const float*)d_in[5];
    const int*   labels = (const int*)d_in[6];

    float* ems  = (float*)d_ws;              // 64*512*21 f32 = 2.75 MB
    float* outp = (float*)d_out;

    emis_kernel<<<dim3((B_NUM * T_LEN) / 64), dim3(256), 0, stream>>>(
        hidden, W, bvec, labels, ems, outp);

    crf_kernel<<<dim3(B_NUM), dim3(64), 0, stream>>>(
        ems, labels, start, endv, trans, outp);
}

// Round 8
// 225.897 us; speedup vs baseline: 1.2525x; 1.0738x over previous
//
#include <hip/hip_runtime.h>

// Problem: B=64, T=512, H=768, C=21
// inputs: hidden(64*512*768 f32), W(768*21 f32), b(21), start(21), end(21),
//         trans(21*21 f32), labels(64*512 int32, -100 = masked, prefix-valid)
// output: scalar f32 loss = mean_b(logZ_b - num_b)

#define T_LEN 512
#define C_NUM 21
#define H_DIM 768
#define B_NUM 64
#define WT_LD 772  // padded leading dim for transposed W in LDS

__device__ __forceinline__ float bcastf(float v, int l) {
    return __int_as_float(__builtin_amdgcn_readlane(__float_as_int(v), l));
}
__device__ __forceinline__ float firstf(float v) {
    return __int_as_float(__builtin_amdgcn_readfirstlane(__float_as_int(v)));
}

// ---------------- Kernel 1: emissions = hidden @ W + b ----------------
// (unchanged from measured R5 version)
__global__ __launch_bounds__(256) void emis_kernel(
    const float* __restrict__ hidden, const float* __restrict__ W,
    const float* __restrict__ bvec, const int* __restrict__ labels,
    float* __restrict__ ems, float* __restrict__ out)
{
    __shared__ __align__(16) float Wt[C_NUM * WT_LD]; // 64848 B
    __shared__ float blds[C_NUM];

    const int tid = threadIdx.x;
    if (blockIdx.x == 0 && tid == 0) out[0] = 0.f;  // init for crf atomics (stream-ordered)

    for (int lin = tid; lin < H_DIM * C_NUM; lin += 256) {
        const int k = lin / C_NUM;            // magic-mul
        const int c = lin - k * C_NUM;
        Wt[c * WT_LD + k] = W[lin];
    }
    if (tid < C_NUM) blds[tid] = bvec[tid];
    __syncthreads();

    const int wid  = tid >> 6;
    const int lane = tid & 63;
    const int rl   = lane >> 4;
    const int q    = lane & 15;
    const int r0   = blockIdx.x * 64 + wid * 16 + rl * 4;  // 4 rows per lane

    bool v[4];
    bool anyv = false;
    #pragma unroll
    for (int rr = 0; rr < 4; ++rr) {
        v[rr] = (labels[r0 + rr] != -100);
        anyv = anyv || v[rr];
    }

    float acc[4][C_NUM];
    #pragma unroll
    for (int rr = 0; rr < 4; ++rr)
        #pragma unroll
        for (int c = 0; c < C_NUM; ++c) acc[rr][c] = 0.f;

    if (anyv) {
        #pragma unroll 2
        for (int m = 0; m < 12; ++m) {
            float4 h[4];
            #pragma unroll
            for (int rr = 0; rr < 4; ++rr)
                h[rr] = *(const float4*)&hidden[(size_t)(r0 + rr) * H_DIM + m * 64 + q * 4];
            #pragma unroll
            for (int c = 0; c < C_NUM; ++c) {
                const float4 w = *(const float4*)&Wt[c * WT_LD + m * 64 + q * 4];
                #pragma unroll
                for (int rr = 0; rr < 4; ++rr) {
                    acc[rr][c] = fmaf(h[rr].w, w.w, fmaf(h[rr].z, w.z,
                                 fmaf(h[rr].y, w.y, fmaf(h[rr].x, w.x, acc[rr][c]))));
                }
            }
        }
    }

    #pragma unroll
    for (int rr = 0; rr < 4; ++rr) {
        #pragma unroll
        for (int c = 0; c < C_NUM; ++c) {
            float s = acc[rr][c];
            s += __shfl_xor(s, 1);
            s += __shfl_xor(s, 2);
            s += __shfl_xor(s, 4);
            s += __shfl_xor(s, 8);
            acc[rr][c] = s;
        }
    }
    if (q == 0) {
        #pragma unroll
        for (int rr = 0; rr < 4; ++rr) {
            if (v[rr]) {
                float* er = ems + (size_t)(r0 + rr) * C_NUM;
                #pragma unroll
                for (int c = 0; c < C_NUM; ++c) er[c] = acc[rr][c] + blds[c];
            }
        }
    }
}

// One linear-space scan step: a <- (sum_i a_i * Ecol_i) * eem
#define SCAN_STEP(EEM)                                                         \
    {                                                                          \
        float y0 = 0.f, y1 = 0.f, y2 = 0.f, y3 = 0.f;                          \
        float y4 = 0.f, y5 = 0.f, y6 = 0.f, y7 = 0.f;                          \
        y0 = fmaf(bcastf(a, 0),  Ecol[0],  y0);                                \
        y1 = fmaf(bcastf(a, 1),  Ecol[1],  y1);                                \
        y2 = fmaf(bcastf(a, 2),  Ecol[2],  y2);                                \
        y3 = fmaf(bcastf(a, 3),  Ecol[3],  y3);                                \
        y4 = fmaf(bcastf(a, 4),  Ecol[4],  y4);                                \
        y5 = fmaf(bcastf(a, 5),  Ecol[5],  y5);                                \
        y6 = fmaf(bcastf(a, 6),  Ecol[6],  y6);                                \
        y7 = fmaf(bcastf(a, 7),  Ecol[7],  y7);                                \
        y0 = fmaf(bcastf(a, 8),  Ecol[8],  y0);                                \
        y1 = fmaf(bcastf(a, 9),  Ecol[9],  y1);                                \
        y2 = fmaf(bcastf(a, 10), Ecol[10], y2);                                \
        y3 = fmaf(bcastf(a, 11), Ecol[11], y3);                                \
        y4 = fmaf(bcastf(a, 12), Ecol[12], y4);                                \
        y5 = fmaf(bcastf(a, 13), Ecol[13], y5);                                \
        y6 = fmaf(bcastf(a, 14), Ecol[14], y6);                                \
        y7 = fmaf(bcastf(a, 15), Ecol[15], y7);                                \
        y0 = fmaf(bcastf(a, 16), Ecol[16], y0);                                \
        y1 = fmaf(bcastf(a, 17), Ecol[17], y1);                                \
        y2 = fmaf(bcastf(a, 18), Ecol[18], y2);                                \
        y3 = fmaf(bcastf(a, 19), Ecol[19], y3);                                \
        y4 = fmaf(bcastf(a, 20), Ecol[20], y4);                                \
        a = (((y0 + y1) + (y2 + y3)) + ((y4 + y5) + (y6 + y7))) * (EEM);       \
    }

#define RESCALE                                                                \
    {                                                                          \
        const float m = firstf(a);                                             \
        const int ebits = (__float_as_int(m) >> 23) & 0xff;                    \
        a *= __int_as_float((254 - ebits) << 23);                              \
        Sacc += (double)(ebits - 127) * 0.6931471805599453;                    \
    }

// ---------------- Kernel 2: CRF forward scan (linear space) + numerator ----------------
// 16-deep register prefetch (2 blocks of 8 ahead): slack ~16 steps ~1760cy,
// robustly covers the ~900cy HBM-miss latency. Exps computed per block off
// the serial chain; exact power-of-2 rescale per block.
__global__ __launch_bounds__(64) void crf_kernel(
    const float* __restrict__ ems, const int* __restrict__ labels,
    const float* __restrict__ start, const float* __restrict__ endv,
    const float* __restrict__ trans, float* __restrict__ out)
{
    const int b    = blockIdx.x;
    const int lane = threadIdx.x;
    const int*   lab = labels + b * T_LEN;
    const float* em  = ems + (size_t)b * T_LEN * C_NUM;

    // ---- numerator + length (mask is a prefix; len >= T/2) ----
    // All label loads issued up-front (independent); lab[t-1] via shuffle.
    int lv[8];
    #pragma unroll
    for (int k = 0; k < 8; ++k) lv[k] = lab[lane + 64 * k];

    float s = 0.f;
    int   cnt = 0;
    #pragma unroll
    for (int k = 0; k < 8; ++k) {
        const int t  = lane + 64 * k;
        const int lt = lv[k];
        int lp = __shfl_up(lv[k], 1);
        if (lane == 0) lp = (k > 0) ? __builtin_amdgcn_readlane(lv[k - 1], 63) : 0;
        if (lt != -100) {
            cnt++;
            // prefix mask: if t valid and t>0, then t-1 valid (lp != -100)
            s += em[t * C_NUM + lt];
            s += (t == 0) ? start[lt] : trans[lp * C_NUM + lt];
        }
    }
    #pragma unroll
    for (int o = 32; o; o >>= 1) {
        s   += __shfl_xor(s, o);
        cnt += __shfl_xor(cnt, o);
    }
    const int len = cnt;
    const float num = s + endv[lab[len - 1]];

    // ---- linear-space forward scan ----
    const int j = lane;
    float Ecol[C_NUM];
    float al0 = -1e30f;
    if (j < C_NUM) {
        #pragma unroll
        for (int i = 0; i < C_NUM; ++i) Ecol[i] = __expf(trans[i * C_NUM + j]);
        al0 = start[j] + em[j];
    } else {
        #pragma unroll
        for (int i = 0; i < C_NUM; ++i) Ecol[i] = 0.f;
    }
    const float M0 = firstf(al0);
    float a = __expf(al0 - M0);          // lanes >= 21: exp(-huge) = 0
    double Sacc = (double)M0;

    const float* ep = em + ((j < C_NUM) ? j : 0);   // lanes >= 21: safe dummy col
    #define LD(T_IDX) ep[((T_IDX) < len ? (T_IDX) : (len - 1)) * C_NUM]

    // Invariant at loop head: rA = raw em for steps t0..t0+7, rB = t0+8..t0+15.
    float rA[8], rB[8];
    #pragma unroll
    for (int i = 0; i < 8; ++i) rA[i] = LD(1 + i);
    #pragma unroll
    for (int i = 0; i < 8; ++i) rB[i] = LD(9 + i);

    int t0 = 1;
    for (; t0 + 15 < len; t0 += 8) {
        // issue loads two blocks ahead (consumed after ~16 steps)
        float c[8];
        #pragma unroll
        for (int i = 0; i < 8; ++i) c[i] = LD(t0 + 16 + i);

        float e[8];
        #pragma unroll
        for (int i = 0; i < 8; ++i) e[i] = __expf(rA[i]);

        SCAN_STEP(e[0]); SCAN_STEP(e[1]); SCAN_STEP(e[2]); SCAN_STEP(e[3]);
        SCAN_STEP(e[4]); SCAN_STEP(e[5]); SCAN_STEP(e[6]); SCAN_STEP(e[7]);
        RESCALE;

        #pragma unroll
        for (int i = 0; i < 8; ++i) { rA[i] = rB[i]; rB[i] = c[i]; }
    }
    // exit: len - t0 in [8,15] -> exactly one full block (rA), then tail from rB
    {
        float e[8];
        #pragma unroll
        for (int i = 0; i < 8; ++i) e[i] = __expf(rA[i]);
        SCAN_STEP(e[0]); SCAN_STEP(e[1]); SCAN_STEP(e[2]); SCAN_STEP(e[3]);
        SCAN_STEP(e[4]); SCAN_STEP(e[5]); SCAN_STEP(e[6]); SCAN_STEP(e[7]);
        RESCALE;
        t0 += 8;
    }
    {
        const int rem = len - t0;   // 0..7
        if (rem > 0) { SCAN_STEP(__expf(rB[0])); }
        if (rem > 1) { SCAN_STEP(__expf(rB[1])); }
        if (rem > 2) { SCAN_STEP(__expf(rB[2])); }
        if (rem > 3) { SCAN_STEP(__expf(rB[3])); }
        if (rem > 4) { SCAN_STEP(__expf(rB[4])); }
        if (rem > 5) { SCAN_STEP(__expf(rB[5])); }
        if (rem > 6) { SCAN_STEP(__expf(rB[6])); }
    }
    #undef LD

    // ---- logZ = Sacc + log(sum_j a_j * exp(end_j)) ----
    float x = 0.f;
    if (j < C_NUM) x = a * __expf(endv[j]);
    float e = x;
    #pragma unroll
    for (int o = 32; o; o >>= 1) e += __shfl_xor(e, o);

    if (lane == 0) {
        const float logZ = (float)(Sacc + (double)__logf(e));
        atomicAdd(out, (logZ - num) * (1.0f / (float)B_NUM));
    }
}

// ---------------- host launch ----------------
extern "C" void kernel_launch(void* const* d_in, const int* in_sizes, int n_in,
                              void* d_out, int out_size, void* d_ws, size_t ws_size,
                              hipStream_t stream) {
    const float* hidden = (const float*)d_in[0];
    const float* W      = (const float*)d_in[1];
    const float* bvec   = (const float*)d_in[2];
    const float* start  = (const float*)d_in[3];
    const float* endv   = (const float*)d_in[4];
    const float* trans  = (const float*)d_in[5];
    const int*   labels = (const int*)d_in[6];

    float* ems  = (float*)d_ws;              // 64*512*21 f32 = 2.75 MB
    float* outp = (float*)d_out;

    emis_kernel<<<dim3((B_NUM * T_LEN) / 64), dim3(256), 0, stream>>>(
        hidden, W, bvec, labels, ems, outp);

    crf_kernel<<<dim3(B_NUM), dim3(64), 0, stream>>>(
        ems, labels, start, endv, trans, outp);
}